// Round 10
// baseline (86.153 us; speedup 1.0000x reference)
//
#include <hip/hip_runtime.h>
#include <math.h>

// CumulativeLayerNorm [B=8, K=8000, H=512] f32.
// out[b,k,h] = gamma[h]*(x[b,k,h]-mean[b,k])*rsqrt(var[b,k]+1e-8)+beta[h],
// mean/var over prefix inputs[b,:k+1,:].
//
// Primary: ONE kernel, 1000 blocks x 1024 threads, one 64-frame segment per
// block held ENTIRELY in dynamic LDS (128 KB, 1 block/CU).
//   phase A: 16 waves x 4 frames: load -> LDS + per-frame sums + f64 block
//            aggregate; publish aggregate + flag (release).
//   wait   : wave0 polls ONLY the s predecessor flags of its own batch
//            (prefix wait, not full barrier) -> early segments write while
//            late segments still read => read/write streams overlap.
//            Deadlock-free: arrival-order vids (atomicAdd) mean a block
//            only waits on earlier arrivals.
//   phase C: normalize from LDS (zero re-read), NT stores.
// HBM bytes = 131 read + 131 write = 262 MB (the compulsory floor).
// Fallback (geometry / dynamic-LDS attr failure): proven R7 2-kernel pipeline.

#define HDIM 512
#define F4H (HDIM / 4)     // 128
#define SEG 64             // frames per segment/block
#define BATCHES 8
#define KLEN 8000
#define SEGS (KLEN / SEG)          // 125
#define NBLK (BATCHES * SEGS)      // 1000

typedef float f32x4 __attribute__((ext_vector_type(4)));
typedef unsigned long long u64;

// ===================== primary: pipelined flag-sync kernel ===============
__global__ __launch_bounds__(1024) void cln_pipe(
    const float* __restrict__ in, const float* __restrict__ gamma,
    const float* __restrict__ beta, float* __restrict__ out,
    double* __restrict__ segS, double* __restrict__ segQ,
    unsigned int* __restrict__ flags, unsigned int* __restrict__ vidctr)
{
    extern __shared__ f32x4 xs[];      // [SEG*F4H] = 128 KB, whole segment
    __shared__ float fsum[SEG], fsq[SEG], meanS[SEG], istdS[SEG];
    __shared__ double wS[16], wQ[16];
    __shared__ unsigned int vid_s;

    const int tid  = threadIdx.x;
    const int lane = tid & 63;
    const int wid  = tid >> 6;         // 0..15

    if (tid == 0) vid_s = atomicAdd(vidctr, 1u);   // arrival-order id
    __syncthreads();
    const unsigned int vid = vid_s;
    const int b = vid & (BATCHES - 1); // vid % 8
    const int s = vid >> 3;            // vid / 8   (0..124)
    const int k0 = s * SEG;
    const int me = b * SEGS + s;

    // gamma/beta for this lane's columns
    const f32x4 g0  = ((const f32x4*)gamma)[lane];
    const f32x4 g1  = ((const f32x4*)gamma)[lane + 64];
    const f32x4 be0 = ((const f32x4*)beta)[lane];
    const f32x4 be1 = ((const f32x4*)beta)[lane + 64];

    const f32x4* p = (const f32x4*)in + ((size_t)b * KLEN + k0) * F4H;

    // ---- phase A: 4 frames per wave -> LDS + sums -----------------------
    double accS = 0.0, accQ = 0.0;
    #pragma unroll
    for (int i = 0; i < 4; ++i) {
        const int f = wid * 4 + i;
        const f32x4 a = p[(size_t)f * F4H + lane];
        const f32x4 c = p[(size_t)f * F4H + 64 + lane];
        xs[f * F4H + lane]      = a;
        xs[f * F4H + 64 + lane] = c;
        float sv = (a.x + a.y) + (a.z + a.w) + (c.x + c.y) + (c.z + c.w);
        float qv = (a.x * a.x + a.y * a.y) + (a.z * a.z + a.w * a.w)
                 + (c.x * c.x + c.y * c.y) + (c.z * c.z + c.w * c.w);
        #pragma unroll
        for (int off = 32; off >= 1; off >>= 1) {
            sv += __shfl_xor(sv, off);
            qv += __shfl_xor(qv, off);
        }
        if (lane == 0) { fsum[f] = sv; fsq[f] = qv; }
        accS += (double)sv;            // wave-uniform
        accQ += (double)qv;
    }
    if (lane == 0) { wS[wid] = accS; wQ[wid] = accQ; }
    __syncthreads();

    // ---- publish aggregate + flag (tid 0), then wave0 prefix-waits ------
    if (tid == 0) {
        double S = 0.0, Q = 0.0;
        #pragma unroll
        for (int w = 0; w < 16; ++w) { S += wS[w]; Q += wQ[w]; }
        __hip_atomic_store((u64*)&segS[me], __double_as_longlong(S),
                           __ATOMIC_RELAXED, __HIP_MEMORY_SCOPE_AGENT);
        __hip_atomic_store((u64*)&segQ[me], __double_as_longlong(Q),
                           __ATOMIC_RELAXED, __HIP_MEMORY_SCOPE_AGENT);
        __hip_atomic_store(&flags[me], 1u,
                           __ATOMIC_RELEASE, __HIP_MEMORY_SCOPE_AGENT);
    }

    if (wid == 0) {
        // wait for the s predecessors of this batch (<=124 -> 2 windows),
        // then sum their aggregates (f64) into an exclusive prefix.
        double es = 0.0, eq = 0.0;
        #pragma unroll
        for (int base = 0; base < SEGS; base += 64) {
            const int j = base + lane;
            const bool need = (j < s);
            const int idx = b * SEGS + (need ? j : 0);
            unsigned int f;
            do {
                f = need ? __hip_atomic_load(&flags[idx], __ATOMIC_ACQUIRE,
                                             __HIP_MEMORY_SCOPE_AGENT)
                         : 1u;
                if (__ballot(f == 0u) == 0ull) break;
                __builtin_amdgcn_s_sleep(8);
            } while (true);
            if (need) {
                es += __longlong_as_double(__hip_atomic_load((u64*)&segS[idx],
                        __ATOMIC_RELAXED, __HIP_MEMORY_SCOPE_AGENT));
                eq += __longlong_as_double(__hip_atomic_load((u64*)&segQ[idx],
                        __ATOMIC_RELAXED, __HIP_MEMORY_SCOPE_AGENT));
            }
        }
        #pragma unroll
        for (int off = 32; off >= 1; off >>= 1) {
            es += __shfl_xor(es, off);
            eq += __shfl_xor(eq, off);
        }
        // inclusive scan over this segment's 64 per-frame sums (lane=frame)
        double sc = (double)fsum[lane], qc = (double)fsq[lane];
        #pragma unroll
        for (int off = 1; off < 64; off <<= 1) {
            double s2 = __shfl_up(sc, off);
            double q2 = __shfl_up(qc, off);
            if (lane >= off) { sc += s2; qc += q2; }
        }
        sc += es; qc += eq;
        const double cnt = (double)(k0 + lane + 1) * (double)HDIM;
        const double m   = sc / cnt;
        const double var = qc / cnt - m * m;
        meanS[lane] = (float)m;
        istdS[lane] = (float)(1.0 / sqrt(var + 1e-8));
    }
    __syncthreads();

    // ---- phase C: normalize straight from LDS, NT stores ----------------
    f32x4* o4 = (f32x4*)out + ((size_t)b * KLEN + k0) * F4H;
    #pragma unroll
    for (int i = 0; i < 4; ++i) {
        const int f = wid * 4 + i;
        const float m = meanS[f];
        const float r = istdS[f];
        const f32x4 a = xs[f * F4H + lane];
        const f32x4 c = xs[f * F4H + 64 + lane];
        f32x4 o0, o1;
        o0.x = g0.x * ((a.x - m) * r) + be0.x;
        o0.y = g0.y * ((a.y - m) * r) + be0.y;
        o0.z = g0.z * ((a.z - m) * r) + be0.z;
        o0.w = g0.w * ((a.w - m) * r) + be0.w;
        o1.x = g1.x * ((c.x - m) * r) + be1.x;
        o1.y = g1.y * ((c.y - m) * r) + be1.y;
        o1.z = g1.z * ((c.z - m) * r) + be1.z;
        o1.w = g1.w * ((c.w - m) * r) + be1.w;
        __builtin_nontemporal_store(o0, o4 + (size_t)f * F4H + lane);
        __builtin_nontemporal_store(o1, o4 + (size_t)f * F4H + 64 + lane);
    }
}

// ===================== fallback: proven R7 2-kernel pipeline =============
__global__ __launch_bounds__(256) void k_seg_sums(
    const float* __restrict__ in, float* __restrict__ ssum,
    float* __restrict__ ssq, double* __restrict__ segS,
    double* __restrict__ segQ, int K, int segsPerBatch)
{
    const int lane = threadIdx.x & 63;
    const int wid  = threadIdx.x >> 6;
    const int segGlobal = blockIdx.x;
    const int b   = segGlobal / segsPerBatch;
    const int seg = segGlobal % segsPerBatch;
    const int k0  = seg * SEG;

    double accS = 0.0, accQ = 0.0;
    #pragma unroll 4
    for (int i = 0; i < SEG / 4; ++i) {
        const int fk = k0 + wid * (SEG / 4) + i;
        if (fk < K) {
            const float4* p = (const float4*)in + ((size_t)b * K + fk) * F4H;
            float4 a = p[lane];
            float4 c = p[lane + 64];
            float s = (a.x + a.y) + (a.z + a.w) + (c.x + c.y) + (c.z + c.w);
            float q = (a.x * a.x + a.y * a.y) + (a.z * a.z + a.w * a.w)
                    + (c.x * c.x + c.y * c.y) + (c.z * c.z + c.w * c.w);
            #pragma unroll
            for (int off = 32; off >= 1; off >>= 1) {
                s += __shfl_xor(s, off);
                q += __shfl_xor(q, off);
            }
            if (lane == 0) {
                ssum[(size_t)b * K + fk] = s;
                ssq[(size_t)b * K + fk]  = q;
            }
            accS += (double)s;
            accQ += (double)q;
        }
    }
    __shared__ double wS[4], wQ[4];
    if (lane == 0) { wS[wid] = accS; wQ[wid] = accQ; }
    __syncthreads();
    if (threadIdx.x == 0) {
        segS[segGlobal] = wS[0] + wS[1] + wS[2] + wS[3];
        segQ[segGlobal] = wQ[0] + wQ[1] + wQ[2] + wQ[3];
    }
}

__global__ __launch_bounds__(256) void k_norm_fused(
    const float* __restrict__ in, const float* __restrict__ gamma,
    const float* __restrict__ beta, const float* __restrict__ ssum,
    const float* __restrict__ ssq, const double* __restrict__ segS,
    const double* __restrict__ segQ, float* __restrict__ out,
    int K, int segsPerBatch)
{
    __shared__ float meanS[SEG], istdS[SEG];

    const int tid  = threadIdx.x;
    const int lane = tid & 63;
    const int wid  = tid >> 6;
    const int b = blockIdx.x / segsPerBatch;
    const int s = blockIdx.x % segsPerBatch;
    const int k0 = s * SEG;

    const f32x4 g0  = ((const f32x4*)gamma)[lane];
    const f32x4 g1  = ((const f32x4*)gamma)[lane + 64];
    const f32x4 be0 = ((const f32x4*)beta)[lane];
    const f32x4 be1 = ((const f32x4*)beta)[lane + 64];

    if (wid == 0) {
        double es = 0.0, eq = 0.0;
        for (int base = 0; base < s; base += 64) {
            const int j = base + lane;
            if (j < s) {
                es += segS[(size_t)b * segsPerBatch + j];
                eq += segQ[(size_t)b * segsPerBatch + j];
            }
        }
        #pragma unroll
        for (int off = 32; off >= 1; off >>= 1) {
            es += __shfl_xor(es, off);
            eq += __shfl_xor(eq, off);
        }
        const int k = k0 + lane;
        double sc = 0.0, qc = 0.0;
        if (k < K) {
            sc = (double)ssum[(size_t)b * K + k];
            qc = (double)ssq[(size_t)b * K + k];
        }
        #pragma unroll
        for (int off = 1; off < 64; off <<= 1) {
            double s2 = __shfl_up(sc, off);
            double q2 = __shfl_up(qc, off);
            if (lane >= off) { sc += s2; qc += q2; }
        }
        sc += es; qc += eq;
        if (k < K) {
            const double cnt = (double)(k + 1) * (double)HDIM;
            const double m   = sc / cnt;
            const double var = qc / cnt - m * m;
            meanS[lane] = (float)m;
            istdS[lane] = (float)(1.0 / sqrt(var + 1e-8));
        }
    }
    __syncthreads();

    #pragma unroll 4
    for (int i = 0; i < SEG / 4; ++i) {
        const int fi = wid * (SEG / 4) + i;
        const int k = k0 + fi;
        if (k < K) {
            const f32x4* p = (const f32x4*)in + ((size_t)b * K + k) * F4H;
            const f32x4 a = p[lane];
            const f32x4 c = p[lane + 64];
            const float m = meanS[fi];
            const float r = istdS[fi];
            f32x4 o0, o1;
            o0.x = g0.x * ((a.x - m) * r) + be0.x;
            o0.y = g0.y * ((a.y - m) * r) + be0.y;
            o0.z = g0.z * ((a.z - m) * r) + be0.z;
            o0.w = g0.w * ((a.w - m) * r) + be0.w;
            o1.x = g1.x * ((c.x - m) * r) + be1.x;
            o1.y = g1.y * ((c.y - m) * r) + be1.y;
            o1.z = g1.z * ((c.z - m) * r) + be1.z;
            o1.w = g1.w * ((c.w - m) * r) + be1.w;
            f32x4* q = (f32x4*)out + ((size_t)b * K + k) * F4H;
            __builtin_nontemporal_store(o0, q + lane);
            __builtin_nontemporal_store(o1, q + lane + 64);
        }
    }
}

// =========================== host launcher ===============================
extern "C" void kernel_launch(void* const* d_in, const int* in_sizes, int n_in,
                              void* d_out, int out_size, void* d_ws, size_t ws_size,
                              hipStream_t stream)
{
    const float* in    = (const float*)d_in[0];
    const float* gamma = (const float*)d_in[1];
    const float* beta  = (const float*)d_in[2];
    float* out = (float*)d_out;

    const int H = in_sizes[1];                  // 512
    const int BK = in_sizes[0] / H;             // B*K
    const int K = BK / BATCHES;                 // 8000
    const int segsPerBatch = (K + SEG - 1) / SEG;   // 125
    const int NSEG = BATCHES * segsPerBatch;        // 1000
    (void)n_in; (void)out_size; (void)ws_size;

    // ws layout: segS/segQ f64 [NSEG] | flags u32 [NSEG] | vidctr u32 |
    //            pad | ssum/ssq f32 [BK] (fallback only)
    double* segS = (double*)d_ws;
    double* segQ = segS + NSEG;
    unsigned int* flags  = (unsigned int*)(segQ + NSEG);
    unsigned int* vidctr = flags + NSEG;
    float* ssum = (float*)(vidctr + 16);
    float* ssq  = ssum + BK;

    const size_t dynLds = (size_t)SEG * F4H * sizeof(f32x4);   // 128 KB

    // primary-path eligibility: exact geometry + dynamic-LDS attr accepted
    bool pipe = (H == HDIM) && (K == KLEN) && (BK == BATCHES * KLEN);
    if (pipe) {
        if (hipFuncSetAttribute((const void*)cln_pipe,
                hipFuncAttributeMaxDynamicSharedMemorySize,
                (int)dynLds) != hipSuccess) pipe = false;
    }

    if (pipe) {
        // zero flags + vid counter (re-done every call / every graph replay)
        hipMemsetAsync(flags, 0, (NSEG + 16) * sizeof(unsigned int), stream);
        cln_pipe<<<dim3(NBLK), dim3(1024), dynLds, stream>>>(
            in, gamma, beta, out, segS, segQ, flags, vidctr);
    } else {
        k_seg_sums<<<dim3(NSEG), dim3(256), 0, stream>>>(
            in, ssum, ssq, segS, segQ, K, segsPerBatch);
        k_norm_fused<<<dim3(NSEG), dim3(256), 0, stream>>>(
            in, gamma, beta, ssum, ssq, segS, segQ, out, K, segsPerBatch);
    }
}

// Round 11
// 65.951 us; speedup vs baseline: 1.3063x; 1.3063x over previous
//
#include <hip/hip_runtime.h>
#include <math.h>

// CumulativeLayerNorm [B=8, K=8000, H=512] f32.
// out[b,k,h] = gamma[h]*(x[b,k,h]-mean[b,k])*rsqrt(var[b,k]+1e-8)+beta[h],
// mean/var over prefix inputs[b,:k+1,:].
//
// Primary: ONE kernel, 1000 blocks x 256 threads (4 blocks/CU -> whole grid
// co-resident, runtime-verified), one 64-frame segment per block; 8 of 16
// frames per wave staged on-chip (4 LDS + 4 regs).
//   phase A: stream 16 frames/wave: sums + stage; publish f64 segment
//            aggregate + per-segment flag (release).
//   wait   : wave0 polls ONLY its s predecessor flags (prefix wait, not a
//            batch barrier) -> early segments normalize+write while late
//            segments still read: read/write streams overlap.
//            Deadlock-free: grid fully resident (checked on host).
//   phase C: normalize; 8 frames re-read (L3-hot), 8 from on-chip; NT out.
// Block map: s = bx>>3, b = bx&7 -> low blockIdx = low segments, so the
// pipeline drains in dispatch order.
// Fallback (geometry/occupancy mismatch): proven R7 2-kernel pipeline.

#define HDIM 512
#define F4H (HDIM / 4)     // 128
#define SEG 64             // frames per segment/block
#define BATCHES 8
#define KLEN 8000
#define SEGS (KLEN / SEG)          // 125
#define NBLK (BATCHES * SEGS)      // 1000

typedef float f32x4 __attribute__((ext_vector_type(4)));
typedef unsigned long long u64;

// ===================== primary: all-resident prefix-wait kernel ==========
__global__ __launch_bounds__(256, 4) void cln_pipe2(
    const float* __restrict__ in, const float* __restrict__ gamma,
    const float* __restrict__ beta, float* __restrict__ out,
    double* __restrict__ segS, double* __restrict__ segQ,
    unsigned int* __restrict__ flags)
{
    __shared__ f32x4 stage[16][F4H];   // 32 KB: 4 frames per wave
    __shared__ float fsum[SEG], fsq[SEG], meanS[SEG], istdS[SEG];
    __shared__ double wS[4], wQ[4];

    const int tid  = threadIdx.x;
    const int lane = tid & 63;
    const int wid  = tid >> 6;
    const int bx   = blockIdx.x;
    const int b    = bx & (BATCHES - 1);   // batch
    const int s    = bx >> 3;              // segment within batch (0..124)
    const int k0   = s * SEG;
    const int me   = b * SEGS + s;

    // gamma/beta for this lane's columns (held in regs)
    const f32x4 g0  = ((const f32x4*)gamma)[lane];
    const f32x4 g1  = ((const f32x4*)gamma)[lane + 64];
    const f32x4 be0 = ((const f32x4*)beta)[lane];
    const f32x4 be1 = ((const f32x4*)beta)[lane + 64];

    const f32x4* p = (const f32x4*)in + ((size_t)b * KLEN + k0 + wid * 16) * F4H;

    // ---- phase A: stream 16 frames/wave; stage 4 LDS + 4 regs -----------
    f32x4 xa[4], xc[4];                // frames 4..7 (32 VGPR)
    double accS = 0.0, accQ = 0.0;
    #pragma unroll
    for (int fi = 0; fi < 16; ++fi) {
        const f32x4 a = p[(size_t)fi * F4H + lane];
        const f32x4 c = p[(size_t)fi * F4H + 64 + lane];
        float sv = (a.x + a.y) + (a.z + a.w) + (c.x + c.y) + (c.z + c.w);
        float qv = (a.x * a.x + a.y * a.y) + (a.z * a.z + a.w * a.w)
                 + (c.x * c.x + c.y * c.y) + (c.z * c.z + c.w * c.w);
        #pragma unroll
        for (int off = 32; off >= 1; off >>= 1) {
            sv += __shfl_xor(sv, off);
            qv += __shfl_xor(qv, off);
        }
        if (lane == 0) { fsum[wid * 16 + fi] = sv; fsq[wid * 16 + fi] = qv; }
        accS += (double)sv;            // wave-uniform
        accQ += (double)qv;
        if (fi < 4) {
            stage[wid * 4 + fi][lane]      = a;
            stage[wid * 4 + fi][64 + lane] = c;
        } else if (fi < 8) {
            xa[fi - 4] = a; xc[fi - 4] = c;
        }
    }
    if (lane == 0) { wS[wid] = accS; wQ[wid] = accQ; }
    __syncthreads();

    // ---- publish aggregate + flag ---------------------------------------
    if (tid == 0) {
        const double S = wS[0] + wS[1] + wS[2] + wS[3];
        const double Q = wQ[0] + wQ[1] + wQ[2] + wQ[3];
        __hip_atomic_store((u64*)&segS[me], __double_as_longlong(S),
                           __ATOMIC_RELAXED, __HIP_MEMORY_SCOPE_AGENT);
        __hip_atomic_store((u64*)&segQ[me], __double_as_longlong(Q),
                           __ATOMIC_RELAXED, __HIP_MEMORY_SCOPE_AGENT);
        __hip_atomic_store(&flags[me], 1u,
                           __ATOMIC_RELEASE, __HIP_MEMORY_SCOPE_AGENT);
    }

    // ---- wait on s predecessors only; build exclusive prefix ------------
    if (wid == 0) {
        double es = 0.0, eq = 0.0;
        #pragma unroll
        for (int base = 0; base < SEGS; base += 64) {   // 2 windows
            const int j = base + lane;
            const bool need = (j < s);
            const int idx = b * SEGS + (need ? j : 0);
            for (;;) {
                const unsigned int f =
                    need ? __hip_atomic_load(&flags[idx], __ATOMIC_ACQUIRE,
                                             __HIP_MEMORY_SCOPE_AGENT)
                         : 1u;
                if (__ballot(f == 0u) == 0ull) break;
                __builtin_amdgcn_s_sleep(8);
            }
            if (need) {
                es += __longlong_as_double(__hip_atomic_load((u64*)&segS[idx],
                        __ATOMIC_RELAXED, __HIP_MEMORY_SCOPE_AGENT));
                eq += __longlong_as_double(__hip_atomic_load((u64*)&segQ[idx],
                        __ATOMIC_RELAXED, __HIP_MEMORY_SCOPE_AGENT));
            }
        }
        #pragma unroll
        for (int off = 32; off >= 1; off >>= 1) {
            es += __shfl_xor(es, off);
            eq += __shfl_xor(eq, off);
        }
        // inclusive scan over this segment's 64 per-frame sums (lane=frame)
        double sc = (double)fsum[lane], qc = (double)fsq[lane];
        #pragma unroll
        for (int off = 1; off < 64; off <<= 1) {
            double s2 = __shfl_up(sc, off);
            double q2 = __shfl_up(qc, off);
            if (lane >= off) { sc += s2; qc += q2; }
        }
        sc += es; qc += eq;
        const double cnt = (double)(k0 + lane + 1) * (double)HDIM;
        const double m   = sc / cnt;
        const double var = qc / cnt - m * m;
        meanS[lane] = (float)m;
        istdS[lane] = (float)(1.0 / sqrt(var + 1e-8));
    }
    __syncthreads();

    // ---- phase C: normalize; re-read frames first (L3-hot) --------------
    f32x4* o4 = (f32x4*)out + ((size_t)b * KLEN + k0 + wid * 16) * F4H;

#define APPLY(fi, a, c) {                                                   \
        const float m = meanS[wid * 16 + (fi)];                             \
        const float r = istdS[wid * 16 + (fi)];                             \
        f32x4 o0, o1;                                                       \
        o0.x = g0.x * ((a.x - m) * r) + be0.x;                              \
        o0.y = g0.y * ((a.y - m) * r) + be0.y;                              \
        o0.z = g0.z * ((a.z - m) * r) + be0.z;                              \
        o0.w = g0.w * ((a.w - m) * r) + be0.w;                              \
        o1.x = g1.x * ((c.x - m) * r) + be1.x;                              \
        o1.y = g1.y * ((c.y - m) * r) + be1.y;                              \
        o1.z = g1.z * ((c.z - m) * r) + be1.z;                              \
        o1.w = g1.w * ((c.w - m) * r) + be1.w;                              \
        __builtin_nontemporal_store(o0, o4 + (size_t)(fi) * F4H + lane);    \
        __builtin_nontemporal_store(o1, o4 + (size_t)(fi) * F4H + 64 + lane); }

    #pragma unroll
    for (int fi = 8; fi < 16; ++fi) {          // re-read from L3/HBM
        const f32x4 a = p[(size_t)fi * F4H + lane];
        const f32x4 c = p[(size_t)fi * F4H + 64 + lane];
        APPLY(fi, a, c);
    }
    #pragma unroll
    for (int fi = 4; fi < 8; ++fi) {           // from registers
        APPLY(fi, xa[fi - 4], xc[fi - 4]);
    }
    #pragma unroll
    for (int fi = 0; fi < 4; ++fi) {           // from LDS
        const f32x4 a = stage[wid * 4 + fi][lane];
        const f32x4 c = stage[wid * 4 + fi][64 + lane];
        APPLY(fi, a, c);
    }
#undef APPLY
}

// ===================== fallback: proven R7 2-kernel pipeline =============
__global__ __launch_bounds__(256) void k_seg_sums(
    const float* __restrict__ in, float* __restrict__ ssum,
    float* __restrict__ ssq, double* __restrict__ segS,
    double* __restrict__ segQ, int K, int segsPerBatch)
{
    const int lane = threadIdx.x & 63;
    const int wid  = threadIdx.x >> 6;
    const int segGlobal = blockIdx.x;
    const int b   = segGlobal / segsPerBatch;
    const int seg = segGlobal % segsPerBatch;
    const int k0  = seg * SEG;

    double accS = 0.0, accQ = 0.0;
    #pragma unroll 4
    for (int i = 0; i < SEG / 4; ++i) {
        const int fk = k0 + wid * (SEG / 4) + i;
        if (fk < K) {
            const float4* p = (const float4*)in + ((size_t)b * K + fk) * F4H;
            float4 a = p[lane];
            float4 c = p[lane + 64];
            float s = (a.x + a.y) + (a.z + a.w) + (c.x + c.y) + (c.z + c.w);
            float q = (a.x * a.x + a.y * a.y) + (a.z * a.z + a.w * a.w)
                    + (c.x * c.x + c.y * c.y) + (c.z * c.z + c.w * c.w);
            #pragma unroll
            for (int off = 32; off >= 1; off >>= 1) {
                s += __shfl_xor(s, off);
                q += __shfl_xor(q, off);
            }
            if (lane == 0) {
                ssum[(size_t)b * K + fk] = s;
                ssq[(size_t)b * K + fk]  = q;
            }
            accS += (double)s;
            accQ += (double)q;
        }
    }
    __shared__ double wS[4], wQ[4];
    if (lane == 0) { wS[wid] = accS; wQ[wid] = accQ; }
    __syncthreads();
    if (threadIdx.x == 0) {
        segS[segGlobal] = wS[0] + wS[1] + wS[2] + wS[3];
        segQ[segGlobal] = wQ[0] + wQ[1] + wQ[2] + wQ[3];
    }
}

__global__ __launch_bounds__(256) void k_norm_fused(
    const float* __restrict__ in, const float* __restrict__ gamma,
    const float* __restrict__ beta, const float* __restrict__ ssum,
    const float* __restrict__ ssq, const double* __restrict__ segS,
    const double* __restrict__ segQ, float* __restrict__ out,
    int K, int segsPerBatch)
{
    __shared__ float meanS[SEG], istdS[SEG];

    const int tid  = threadIdx.x;
    const int lane = tid & 63;
    const int wid  = tid >> 6;
    const int b = blockIdx.x / segsPerBatch;
    const int s = blockIdx.x % segsPerBatch;
    const int k0 = s * SEG;

    const f32x4 g0  = ((const f32x4*)gamma)[lane];
    const f32x4 g1  = ((const f32x4*)gamma)[lane + 64];
    const f32x4 be0 = ((const f32x4*)beta)[lane];
    const f32x4 be1 = ((const f32x4*)beta)[lane + 64];

    if (wid == 0) {
        double es = 0.0, eq = 0.0;
        for (int base = 0; base < s; base += 64) {
            const int j = base + lane;
            if (j < s) {
                es += segS[(size_t)b * segsPerBatch + j];
                eq += segQ[(size_t)b * segsPerBatch + j];
            }
        }
        #pragma unroll
        for (int off = 32; off >= 1; off >>= 1) {
            es += __shfl_xor(es, off);
            eq += __shfl_xor(eq, off);
        }
        const int k = k0 + lane;
        double sc = 0.0, qc = 0.0;
        if (k < K) {
            sc = (double)ssum[(size_t)b * K + k];
            qc = (double)ssq[(size_t)b * K + k];
        }
        #pragma unroll
        for (int off = 1; off < 64; off <<= 1) {
            double s2 = __shfl_up(sc, off);
            double q2 = __shfl_up(qc, off);
            if (lane >= off) { sc += s2; qc += q2; }
        }
        sc += es; qc += eq;
        if (k < K) {
            const double cnt = (double)(k + 1) * (double)HDIM;
            const double m   = sc / cnt;
            const double var = qc / cnt - m * m;
            meanS[lane] = (float)m;
            istdS[lane] = (float)(1.0 / sqrt(var + 1e-8));
        }
    }
    __syncthreads();

    #pragma unroll 4
    for (int i = 0; i < SEG / 4; ++i) {
        const int fi = wid * (SEG / 4) + i;
        const int k = k0 + fi;
        if (k < K) {
            const f32x4* p = (const f32x4*)in + ((size_t)b * K + k) * F4H;
            const f32x4 a = p[lane];
            const f32x4 c = p[lane + 64];
            const float m = meanS[fi];
            const float r = istdS[fi];
            f32x4 o0, o1;
            o0.x = g0.x * ((a.x - m) * r) + be0.x;
            o0.y = g0.y * ((a.y - m) * r) + be0.y;
            o0.z = g0.z * ((a.z - m) * r) + be0.z;
            o0.w = g0.w * ((a.w - m) * r) + be0.w;
            o1.x = g1.x * ((c.x - m) * r) + be1.x;
            o1.y = g1.y * ((c.y - m) * r) + be1.y;
            o1.z = g1.z * ((c.z - m) * r) + be1.z;
            o1.w = g1.w * ((c.w - m) * r) + be1.w;
            f32x4* q = (f32x4*)out + ((size_t)b * K + k) * F4H;
            __builtin_nontemporal_store(o0, q + lane);
            __builtin_nontemporal_store(o1, q + lane + 64);
        }
    }
}

// =========================== host launcher ===============================
extern "C" void kernel_launch(void* const* d_in, const int* in_sizes, int n_in,
                              void* d_out, int out_size, void* d_ws, size_t ws_size,
                              hipStream_t stream)
{
    const float* in    = (const float*)d_in[0];
    const float* gamma = (const float*)d_in[1];
    const float* beta  = (const float*)d_in[2];
    float* out = (float*)d_out;

    const int H = in_sizes[1];                  // 512
    const int BK = in_sizes[0] / H;             // B*K
    const int K = BK / BATCHES;                 // 8000
    const int segsPerBatch = (K + SEG - 1) / SEG;   // 125
    const int NSEG = BATCHES * segsPerBatch;        // 1000
    (void)n_in; (void)out_size; (void)ws_size;

    // ws layout: segS/segQ f64 [NSEG] | flags u32 [NSEG] | pad |
    //            ssum/ssq f32 [BK] (fallback only)
    double* segS = (double*)d_ws;
    double* segQ = segS + NSEG;
    unsigned int* flags = (unsigned int*)(segQ + NSEG);
    float* ssum = (float*)(flags + NSEG + 16);
    float* ssq  = ssum + BK;

    // primary-path eligibility: exact geometry + FULL grid co-residency
    bool pipe = (H == HDIM) && (K == KLEN) && (BK == BATCHES * KLEN);
    if (pipe) {
        int dev = 0, nb = 0, cus = 0;
        if (hipGetDevice(&dev) != hipSuccess) pipe = false;
        if (pipe && hipOccupancyMaxActiveBlocksPerMultiprocessor(
                        &nb, (const void*)cln_pipe2, 256, 0) != hipSuccess)
            pipe = false;
        if (pipe && hipDeviceGetAttribute(&cus, hipDeviceAttributeMultiprocessorCount,
                                          dev) != hipSuccess) pipe = false;
        if (pipe && (long)nb * cus < NBLK) pipe = false;
    }

    if (pipe) {
        hipMemsetAsync(flags, 0, NSEG * sizeof(unsigned int), stream);
        cln_pipe2<<<dim3(NBLK), dim3(256), 0, stream>>>(
            in, gamma, beta, out, segS, segQ, flags);
    } else {
        k_seg_sums<<<dim3(NSEG), dim3(256), 0, stream>>>(
            in, ssum, ssq, segS, segQ, K, segsPerBatch);
        k_norm_fused<<<dim3(NSEG), dim3(256), 0, stream>>>(
            in, gamma, beta, ssum, ssq, segS, segQ, out, K, segsPerBatch);
    }
}